// Round 3
// baseline (242.302 us; speedup 1.0000x reference)
//
#include <hip/hip_runtime.h>

#define EPS 1e-5f
#define B 16
#define CH 22
#define T_IN 1001
#define F 36
#define RF 65
#define T1 937            // T_IN - RF + 1
#define FC 792            // F*CH
#define UN 885            // valid u range for Q/E
#define PS3 112           // qconv staged span per f row (need 106, pad to 112)
#define KS 15
#define GN 295
#define WN 129
#define M43 43
#define BF 576            // B*F
#define FLAT 1548         // F*43

// workspace float offsets
#define H2_OFF  0                 // 576*937       =   539,712
#define A_OFF   539712            // A[bf][u]: 576*885 = 509,760
#define WTT_OFF 4617792           // + 36*65       =     2,340 (legacy, unused)
#define WST_OFF 4620132           // + 792*36      =    28,512
#define WCT_OFF 4648644           // + 36*15*36    =    19,440
#define BN_OFF  4668084           // + 6*36        =       216

__device__ __forceinline__ float elu_f(float v) {
    return v > 0.f ? v : (__expf(v) - 1.f);
}

// ---- prep: transpose weights + bn scale/offset + init out with bias --------
__global__ __launch_bounds__(256) void k_prep(
    const float* __restrict__ w_t, const float* __restrict__ w_s,
    const float* __restrict__ w_c,
    const float* __restrict__ b_t, const float* __restrict__ g_t,
    const float* __restrict__ be_t,const float* __restrict__ m_t,
    const float* __restrict__ v_t,
    const float* __restrict__ b_s, const float* __restrict__ g_s,
    const float* __restrict__ be_s,const float* __restrict__ m_s,
    const float* __restrict__ v_s,
    const float* __restrict__ b_c, const float* __restrict__ g_c,
    const float* __restrict__ be_c,const float* __restrict__ m_c,
    const float* __restrict__ v_c, const float* __restrict__ b_fc,
    float* __restrict__ wtT, float* __restrict__ wsT,
    float* __restrict__ wcT, float* __restrict__ bnz,
    float* __restrict__ out)
{
    int i = blockIdx.x * 256 + threadIdx.x;
    if (i < F * RF)     { int k = i / F,  fi = i % F; wtT[i] = w_t[fi * RF + k]; }
    if (i < FC * F)     { int fc = i / F, fo = i % F; wsT[i] = w_s[fo * FC + fc]; }
    if (i < F * KS * F) { int fk = i / F, fo = i % F; int f = fk / KS, k = fk % KS;
                          wcT[i] = w_c[(fo * F + f) * KS + k]; }
    if (i < F) {
        float s1 = g_t[i] * rsqrtf(v_t[i] + EPS);
        bnz[i]          = s1;
        bnz[F + i]      = (b_t[i] - m_t[i]) * s1 + be_t[i];
        float s2 = g_s[i] * rsqrtf(v_s[i] + EPS);
        bnz[2 * F + i]  = s2;
        bnz[3 * F + i]  = (b_s[i] - m_s[i]) * s2 + be_s[i];
        float s3 = g_c[i] * rsqrtf(v_c[i] + EPS);
        bnz[4 * F + i]  = s3;
        bnz[5 * F + i]  = (b_c[i] - m_c[i]) * s3 + be_c[i];
    }
    if (i < B * 4) out[i] = b_fc[i & 3];
}

// ---- K1: FUSED temporal conv + bn_t + elu + 1x1 spatial conv + bn_s + elu --
// Block = (64-t tile, b): grid (15, B) = 240 blocks, 1024 thr = 16 waves.
// Wave (q,g): ch-quarter q (6/6/5/5), fi-group g (9 fi). h1 lives in
// registers (never touches global). Lanes span t only -> all weight reads
// are wave-uniform s_loads. 16 K-partials combine via 4-round LDS tree.
__global__ __launch_bounds__(1024) void k_fused(
    const float* __restrict__ x, const float* __restrict__ w_t,
    const float* __restrict__ wsT, const float* __restrict__ bnz,
    float* __restrict__ h2)
{
    __shared__ float xs[CH * 128];        // 11.3 KB
    __shared__ float comb[8][64][F];      // 73.7 KB (rows 144 B, 16B-aligned)
    const int tid  = threadIdx.x;
    const int lane = tid & 63;
    const int w = __builtin_amdgcn_readfirstlane(tid >> 6);  // 0..15
    const int q = w >> 2;       // ch quarter
    const int g = w & 3;        // fi group
    const int b  = blockIdx.y;
    const int t0 = blockIdx.x * 64;

    // stage x window [22 ch][128 t] once (clamped; garbage only for invalid t)
    for (int i = tid; i < CH * 128; i += 1024) {
        int ch = i >> 7, j = i & 127;
        int t = t0 + j; if (t > T_IN - 1) t = T_IN - 1;
        xs[i] = x[(b * CH + ch) * T_IN + t];
    }
    __syncthreads();

    const int ch0 = (q < 2) ? q * 6 : 12 + (q - 2) * 5;
    const int nch = (q < 2) ? 6 : 5;
    const int fi0 = g * 9;

    float acc[F];
    #pragma unroll
    for (int j = 0; j < F; ++j) acc[j] = 0.f;

    for (int c = 0; c < nch; ++c) {
        const int ch = ch0 + c;
        const float* xr = xs + ch * 128 + lane;
        const float* wt = w_t + fi0 * RF;          // 9 contiguous 65-rows

        float h1a[9];
        #pragma unroll
        for (int j = 0; j < 9; ++j) h1a[j] = 0.f;

        #pragma unroll
        for (int k = 0; k < RF; ++k) {             // 65 ds_read (pairs merge),
            float xv = xr[k];                      // 585 FMA, s_loads x16-merged
            #pragma unroll
            for (int j = 0; j < 9; ++j)
                h1a[j] += xv * wt[j * RF + k];
        }
        #pragma unroll
        for (int j = 0; j < 9; ++j) {              // bn_t + elu in-register
            float s1 = bnz[fi0 + j], o1 = bnz[F + fi0 + j];
            h1a[j] = elu_f(h1a[j] * s1 + o1);
        }
        #pragma unroll
        for (int j = 0; j < 9; ++j) {              // sconv partial: 324 FMA
            const float* wr = wsT + ((fi0 + j) * CH + ch) * F;  // 36 consec
            float e = h1a[j];
            #pragma unroll
            for (int fo = 0; fo < F; ++fo)
                acc[fo] += e * wr[fo];
        }
    }

    // combine 16 K-partials -> wave 0 (4 rounds, float4 LDS)
    for (int half = 8; half >= 1; half >>= 1) {
        if (w >= half && w < 2 * half) {
            float4* cb = (float4*)&comb[w - half][lane][0];
            #pragma unroll
            for (int j = 0; j < 9; ++j)
                cb[j] = make_float4(acc[4*j], acc[4*j+1], acc[4*j+2], acc[4*j+3]);
        }
        __syncthreads();
        if (w < half) {
            const float4* cb = (const float4*)&comb[w][lane][0];
            #pragma unroll
            for (int j = 0; j < 9; ++j) {
                float4 v = cb[j];
                acc[4*j]   += v.x; acc[4*j+1] += v.y;
                acc[4*j+2] += v.z; acc[4*j+3] += v.w;
            }
        }
        __syncthreads();
    }

    if (w == 0) {
        int t = t0 + lane;
        if (t < T1) {
            #pragma unroll
            for (int fo = 0; fo < F; ++fo) {
                float s2 = bnz[2 * F + fo], o2 = bnz[3 * F + fo];
                h2[(b * F + fo) * T1 + t] = elu_f(acc[fo] * s2 + o2);
            }
        }
    }
}

// ---- K2: fused pool3 + dilated conv + bn_c + elu -> A[bf][u] ---------------
// Same pattern: 12 waves, wave = 3-f K-slice with PRIVATE Ps staging (no
// barriers in main loop), acc[36] in registers, weights s_load-uniform,
// 3-round combine tree. grid (14, B) = 224 blocks x 768 thr.
__global__ __launch_bounds__(768) void k_qconv(
    const float* __restrict__ h2, const float* __restrict__ wcT,
    const float* __restrict__ bnz, float* __restrict__ A)
{
    __shared__ float Ps[12][3][PS3];      // 16.1 KB
    __shared__ float comb[6][64][F];      // 55.3 KB
    const int tid  = threadIdx.x;
    const int lane = tid & 63;
    const int w = __builtin_amdgcn_readfirstlane(tid >> 6);  // 0..11
    const int b  = blockIdx.y;
    const int u0 = blockIdx.x * 64;
    const int f0 = w * 3;

    // per-wave private pooled staging (same-wave dep -> compiler lgkmcnt)
    for (int i = lane; i < 3 * PS3; i += 64) {
        int fl = i / PS3, j = i % PS3;
        const float* hr = h2 + (size_t)(b * F + f0 + fl) * T1;
        int s = u0 + j;
        int s0 = s     < T1 - 1 ? s     : T1 - 1;
        int s1 = s + 1 < T1 - 1 ? s + 1 : T1 - 1;
        int s2 = s + 2 < T1 - 1 ? s + 2 : T1 - 1;
        Ps[w][fl][j] = (hr[s0] + hr[s1] + hr[s2]) * (1.f / 3.f);
    }

    float acc[F];
    #pragma unroll
    for (int j = 0; j < F; ++j) acc[j] = 0.f;

    #pragma unroll
    for (int fl = 0; fl < 3; ++fl) {
        #pragma unroll
        for (int k = 0; k < KS; ++k) {
            float pv = Ps[w][fl][lane + 3 * k];
            const float* wr = wcT + ((f0 + fl) * KS + k) * F;  // 36 consec
            #pragma unroll
            for (int fo = 0; fo < F; ++fo) acc[fo] += pv * wr[fo];
        }
    }

    // combine 12 -> 1: rounds 6, 3, then 2-buffer finish
    if (w >= 6) {
        float4* cb = (float4*)&comb[w - 6][lane][0];
        #pragma unroll
        for (int j = 0; j < 9; ++j)
            cb[j] = make_float4(acc[4*j], acc[4*j+1], acc[4*j+2], acc[4*j+3]);
    }
    __syncthreads();
    if (w < 6) {
        const float4* cb = (const float4*)&comb[w][lane][0];
        #pragma unroll
        for (int j = 0; j < 9; ++j) {
            float4 v = cb[j];
            acc[4*j] += v.x; acc[4*j+1] += v.y; acc[4*j+2] += v.z; acc[4*j+3] += v.w;
        }
    }
    __syncthreads();
    if (w >= 3 && w < 6) {
        float4* cb = (float4*)&comb[w - 3][lane][0];
        #pragma unroll
        for (int j = 0; j < 9; ++j)
            cb[j] = make_float4(acc[4*j], acc[4*j+1], acc[4*j+2], acc[4*j+3]);
    }
    __syncthreads();
    if (w < 3) {
        const float4* cb = (const float4*)&comb[w][lane][0];
        #pragma unroll
        for (int j = 0; j < 9; ++j) {
            float4 v = cb[j];
            acc[4*j] += v.x; acc[4*j+1] += v.y; acc[4*j+2] += v.z; acc[4*j+3] += v.w;
        }
    }
    __syncthreads();
    if (w == 1 || w == 2) {
        float4* cb = (float4*)&comb[w - 1][lane][0];
        #pragma unroll
        for (int j = 0; j < 9; ++j)
            cb[j] = make_float4(acc[4*j], acc[4*j+1], acc[4*j+2], acc[4*j+3]);
    }
    __syncthreads();
    if (w == 0) {
        #pragma unroll
        for (int j = 0; j < 9; ++j) {
            float4 v0 = ((const float4*)&comb[0][lane][0])[j];
            float4 v1 = ((const float4*)&comb[1][lane][0])[j];
            acc[4*j]   += v0.x + v1.x; acc[4*j+1] += v0.y + v1.y;
            acc[4*j+2] += v0.z + v1.z; acc[4*j+3] += v0.w + v1.w;
        }
        int u_g = u0 + lane;
        if (u_g < UN) {
            #pragma unroll
            for (int fo = 0; fo < F; ++fo) {
                float sc = bnz[4 * F + fo], oc = bnz[5 * F + fo];
                A[((size_t)(b * F + fo)) * UN + u_g] = elu_f(acc[fo] * sc + oc);
            }
        }
    }
}

// ---- K3: window sums over finished A + fused FC -> atomicAdd out -----------
__global__ __launch_bounds__(256) void k_wins(
    const float* __restrict__ A, const float* __restrict__ w_fc,
    float* __restrict__ out)
{
    __shared__ float Es[UN];
    __shared__ float G[GN];
    __shared__ float Ws[WN];
    __shared__ float Sm[M43];
    const int tid = threadIdx.x;
    const int bf = blockIdx.x;
    const int b = bf / F, f = bf % F;
    for (int i = tid; i < UN; i += 256)
        Es[i] = A[(size_t)bf * UN + i];
    __syncthreads();
    for (int q = tid; q < GN; q += 256)
        G[q] = Es[3 * q] + Es[3 * q + 1] + Es[3 * q + 2];
    __syncthreads();
    if (tid < WN) {
        float a = 0.f;
        for (int q = tid; q < tid + 167; ++q) a += G[q];
        Ws[tid] = a;
    }
    __syncthreads();
    if (tid < M43)
        Sm[tid] = (Ws[3 * tid] + Ws[3 * tid + 1] + Ws[3 * tid + 2]) * (1.f / 3.f);
    __syncthreads();
    if (tid < 4) {
        const float* wr = w_fc + tid * FLAT + f * M43;
        float a = 0.f;
        #pragma unroll 43
        for (int m = 0; m < M43; ++m) a += Sm[m] * wr[m];
        atomicAdd(&out[b * 4 + tid], a * (1.f / 501.f));
    }
}

extern "C" void kernel_launch(void* const* d_in, const int* in_sizes, int n_in,
                              void* d_out, int out_size, void* d_ws, size_t ws_size,
                              hipStream_t stream) {
    const float* x    = (const float*)d_in[0];
    const float* w_t  = (const float*)d_in[1];
    const float* b_t  = (const float*)d_in[2];
    const float* g_t  = (const float*)d_in[3];
    const float* be_t = (const float*)d_in[4];
    const float* m_t  = (const float*)d_in[5];
    const float* v_t  = (const float*)d_in[6];
    const float* w_s  = (const float*)d_in[7];
    const float* b_s  = (const float*)d_in[8];
    const float* g_s  = (const float*)d_in[9];
    const float* be_s = (const float*)d_in[10];
    const float* m_s  = (const float*)d_in[11];
    const float* v_s  = (const float*)d_in[12];
    const float* w_c  = (const float*)d_in[13];
    const float* b_c  = (const float*)d_in[14];
    const float* g_c  = (const float*)d_in[15];
    const float* be_c = (const float*)d_in[16];
    const float* m_c  = (const float*)d_in[17];
    const float* v_c  = (const float*)d_in[18];
    const float* w_fc = (const float*)d_in[19];
    const float* b_fc = (const float*)d_in[20];

    float* ws  = (float*)d_ws;
    float* h2  = ws + H2_OFF;
    float* A   = ws + A_OFF;
    float* wtT = ws + WTT_OFF;
    float* wsT = ws + WST_OFF;
    float* wcT = ws + WCT_OFF;
    float* bnz = ws + BN_OFF;
    float* out = (float*)d_out;

    k_prep<<<dim3(112), 256, 0, stream>>>(
        w_t, w_s, w_c, b_t, g_t, be_t, m_t, v_t,
        b_s, g_s, be_s, m_s, v_s, b_c, g_c, be_c, m_c, v_c, b_fc,
        wtT, wsT, wcT, bnz, out);

    k_fused<<<dim3(15, B), 1024, 0, stream>>>(x, w_t, wsT, bnz, h2);
    k_qconv<<<dim3(14, B), 768, 0, stream>>>(h2, wcT, bnz, A);
    k_wins<<<dim3(BF), 256, 0, stream>>>(A, w_fc, out);
}

// Round 4
// 236.968 us; speedup vs baseline: 1.0225x; 1.0225x over previous
//
#include <hip/hip_runtime.h>

#define EPS 1e-5f
#define B 16
#define CH 22
#define T_IN 1001
#define F 36
#define RF 65
#define T1 937            // T_IN - RF + 1
#define FC 792            // F*CH
#define UN 885            // valid u range for Q/E
#define PS3 112           // qconv staged span per f row (need 106, pad to 112)
#define KS 15
#define GN 295
#define WN 129
#define M43 43
#define BF 576            // B*F
#define FLAT 1548         // F*43

// workspace float offsets
#define H2_OFF  0                 // 576*937       =   539,712
#define A_OFF   539712            // A[bf][u]: 576*885 = 509,760
#define WTT_OFF 4617792           // + 65*36       =     2,340  (wtT[k][fi])
#define WST_OFF 4620132           // + 792*36      =    28,512
#define WCT_OFF 4648644           // + 36*15*36    =    19,440
#define BN_OFF  4668084           // + 6*36        =       216

__device__ __forceinline__ float elu_f(float v) {
    return v > 0.f ? v : (__expf(v) - 1.f);
}

// ---- prep: transpose weights + bn scale/offset + init out with bias --------
__global__ __launch_bounds__(256) void k_prep(
    const float* __restrict__ w_t, const float* __restrict__ w_s,
    const float* __restrict__ w_c,
    const float* __restrict__ b_t, const float* __restrict__ g_t,
    const float* __restrict__ be_t,const float* __restrict__ m_t,
    const float* __restrict__ v_t,
    const float* __restrict__ b_s, const float* __restrict__ g_s,
    const float* __restrict__ be_s,const float* __restrict__ m_s,
    const float* __restrict__ v_s,
    const float* __restrict__ b_c, const float* __restrict__ g_c,
    const float* __restrict__ be_c,const float* __restrict__ m_c,
    const float* __restrict__ v_c, const float* __restrict__ b_fc,
    float* __restrict__ wtT, float* __restrict__ wsT,
    float* __restrict__ wcT, float* __restrict__ bnz,
    float* __restrict__ out)
{
    int i = blockIdx.x * 256 + threadIdx.x;
    if (i < F * RF)     { int k = i / F,  fi = i % F; wtT[i] = w_t[fi * RF + k]; }
    if (i < FC * F)     { int fc = i / F, fo = i % F; wsT[i] = w_s[fo * FC + fc]; }
    if (i < F * KS * F) { int fk = i / F, fo = i % F; int f = fk / KS, k = fk % KS;
                          wcT[i] = w_c[(fo * F + f) * KS + k]; }
    if (i < F) {
        float s1 = g_t[i] * rsqrtf(v_t[i] + EPS);
        bnz[i]          = s1;
        bnz[F + i]      = (b_t[i] - m_t[i]) * s1 + be_t[i];
        float s2 = g_s[i] * rsqrtf(v_s[i] + EPS);
        bnz[2 * F + i]  = s2;
        bnz[3 * F + i]  = (b_s[i] - m_s[i]) * s2 + be_s[i];
        float s3 = g_c[i] * rsqrtf(v_c[i] + EPS);
        bnz[4 * F + i]  = s3;
        bnz[5 * F + i]  = (b_c[i] - m_c[i]) * s3 + be_c[i];
    }
    if (i < B * 4) out[i] = b_fc[i & 3];
}

// ---- K1: FUSED temporal conv + bn_t + elu + 1x1 spatial conv + bn_s + elu --
// Block = (64-t tile, b): grid (15, B) = 240 blocks, 1024 thr = 16 waves.
// LDS 85KB -> exactly 1 block/CU -> 16 waves/CU = 4 waves/SIMD, so the
// correct VGPR budget is 512/4 = 128: __launch_bounds__(1024, 4).
// (Round-3 let the compiler pick 64 VGPRs -> 56 MB/dispatch scratch spills.)
// Wave (q,g): ch-quarter q (6/6/5/5), fi-group g (9 fi). h1 in registers.
// Weight reads via wtT[k][fi]: per k one contiguous 9-float wave-uniform run.
__global__ __launch_bounds__(1024, 4) void k_fused(
    const float* __restrict__ x, const float* __restrict__ wtT,
    const float* __restrict__ wsT, const float* __restrict__ bnz,
    float* __restrict__ h2)
{
    __shared__ float xs[CH * 128];        // 11.3 KB
    __shared__ float comb[8][64][F];      // 73.7 KB (rows 144 B, 16B-aligned)
    const int tid  = threadIdx.x;
    const int lane = tid & 63;
    const int w = __builtin_amdgcn_readfirstlane(tid >> 6);  // 0..15
    const int q = w >> 2;       // ch quarter
    const int g = w & 3;        // fi group
    const int b  = blockIdx.y;
    const int t0 = blockIdx.x * 64;

    // stage x window [22 ch][128 t] once (clamped; garbage only for t >= T1)
    for (int i = tid; i < CH * 128; i += 1024) {
        int ch = i >> 7, j = i & 127;
        int t = t0 + j; if (t > T_IN - 1) t = T_IN - 1;
        xs[i] = x[(b * CH + ch) * T_IN + t];
    }
    __syncthreads();

    const int ch0 = (q < 2) ? q * 6 : 12 + (q - 2) * 5;
    const int nch = (q < 2) ? 6 : 5;
    const int fi0 = g * 9;

    float acc[F];
    #pragma unroll
    for (int j = 0; j < F; ++j) acc[j] = 0.f;

    for (int c = 0; c < nch; ++c) {
        const int ch = ch0 + c;
        const float* xr = xs + ch * 128 + lane;

        float h1a[9];
        #pragma unroll
        for (int j = 0; j < 9; ++j) h1a[j] = 0.f;

        // k in chunks of 8 bounds live SGPR ranges; per k the 9 weights are
        // one contiguous wave-uniform run at wtT + k*F + fi0 (s_load_dwordx8).
        for (int kb = 0; kb < 8; ++kb) {
            #pragma unroll
            for (int k8 = 0; k8 < 8; ++k8) {
                const int k = kb * 8 + k8;
                float xv = xr[k];
                const float* wt = wtT + k * F + fi0;
                #pragma unroll
                for (int j = 0; j < 9; ++j)
                    h1a[j] += xv * wt[j];
            }
        }
        {   // tail k = 64
            float xv = xr[64];
            const float* wt = wtT + 64 * F + fi0;
            #pragma unroll
            for (int j = 0; j < 9; ++j) h1a[j] += xv * wt[j];
        }

        #pragma unroll
        for (int j = 0; j < 9; ++j) {              // bn_t + elu in-register
            float s1 = bnz[fi0 + j], o1 = bnz[F + fi0 + j];
            h1a[j] = elu_f(h1a[j] * s1 + o1);
        }
        #pragma unroll
        for (int j = 0; j < 9; ++j) {              // sconv partial
            const float* wr = wsT + ((fi0 + j) * CH + ch) * F;  // 36 consec
            float e = h1a[j];
            #pragma unroll
            for (int fo = 0; fo < F; ++fo)
                acc[fo] += e * wr[fo];
        }
    }

    // combine 16 K-partials -> wave 0 (4 rounds, float4 LDS)
    for (int half = 8; half >= 1; half >>= 1) {
        if (w >= half && w < 2 * half) {
            float4* cb = (float4*)&comb[w - half][lane][0];
            #pragma unroll
            for (int j = 0; j < 9; ++j)
                cb[j] = make_float4(acc[4*j], acc[4*j+1], acc[4*j+2], acc[4*j+3]);
        }
        __syncthreads();
        if (w < half) {
            const float4* cb = (const float4*)&comb[w][lane][0];
            #pragma unroll
            for (int j = 0; j < 9; ++j) {
                float4 v = cb[j];
                acc[4*j]   += v.x; acc[4*j+1] += v.y;
                acc[4*j+2] += v.z; acc[4*j+3] += v.w;
            }
        }
        __syncthreads();
    }

    if (w == 0) {
        int t = t0 + lane;
        if (t < T1) {
            #pragma unroll
            for (int fo = 0; fo < F; ++fo) {
                float s2 = bnz[2 * F + fo], o2 = bnz[3 * F + fo];
                h2[(b * F + fo) * T1 + t] = elu_f(acc[fo] * s2 + o2);
            }
        }
    }
}

// ---- K2: fused pool3 + dilated conv + bn_c + elu -> A[bf][u] ---------------
// 12 waves, wave = 3-f K-slice with PRIVATE Ps staging (no barriers in main
// loop), acc[36] in registers, weights s_load-uniform, combine tree.
// 12 waves/block, 1 block/CU -> 3 waves/SIMD -> declare (768, 3).
__global__ __launch_bounds__(768, 3) void k_qconv(
    const float* __restrict__ h2, const float* __restrict__ wcT,
    const float* __restrict__ bnz, float* __restrict__ A)
{
    __shared__ float Ps[12][3][PS3];      // 16.1 KB
    __shared__ float comb[6][64][F];      // 55.3 KB
    const int tid  = threadIdx.x;
    const int lane = tid & 63;
    const int w = __builtin_amdgcn_readfirstlane(tid >> 6);  // 0..11
    const int b  = blockIdx.y;
    const int u0 = blockIdx.x * 64;
    const int f0 = w * 3;

    // per-wave private pooled staging (same-wave dep -> compiler lgkmcnt)
    for (int i = lane; i < 3 * PS3; i += 64) {
        int fl = i / PS3, j = i % PS3;
        const float* hr = h2 + (size_t)(b * F + f0 + fl) * T1;
        int s = u0 + j;
        int s0 = s     < T1 - 1 ? s     : T1 - 1;
        int s1 = s + 1 < T1 - 1 ? s + 1 : T1 - 1;
        int s2 = s + 2 < T1 - 1 ? s + 2 : T1 - 1;
        Ps[w][fl][j] = (hr[s0] + hr[s1] + hr[s2]) * (1.f / 3.f);
    }

    float acc[F];
    #pragma unroll
    for (int j = 0; j < F; ++j) acc[j] = 0.f;

    #pragma unroll
    for (int fl = 0; fl < 3; ++fl) {
        #pragma unroll
        for (int k = 0; k < KS; ++k) {
            float pv = Ps[w][fl][lane + 3 * k];
            const float* wr = wcT + ((f0 + fl) * KS + k) * F;  // 36 consec
            #pragma unroll
            for (int fo = 0; fo < F; ++fo) acc[fo] += pv * wr[fo];
        }
    }

    // combine 12 -> 1: rounds 6, 3, then 2-buffer finish
    if (w >= 6) {
        float4* cb = (float4*)&comb[w - 6][lane][0];
        #pragma unroll
        for (int j = 0; j < 9; ++j)
            cb[j] = make_float4(acc[4*j], acc[4*j+1], acc[4*j+2], acc[4*j+3]);
    }
    __syncthreads();
    if (w < 6) {
        const float4* cb = (const float4*)&comb[w][lane][0];
        #pragma unroll
        for (int j = 0; j < 9; ++j) {
            float4 v = cb[j];
            acc[4*j] += v.x; acc[4*j+1] += v.y; acc[4*j+2] += v.z; acc[4*j+3] += v.w;
        }
    }
    __syncthreads();
    if (w >= 3 && w < 6) {
        float4* cb = (float4*)&comb[w - 3][lane][0];
        #pragma unroll
        for (int j = 0; j < 9; ++j)
            cb[j] = make_float4(acc[4*j], acc[4*j+1], acc[4*j+2], acc[4*j+3]);
    }
    __syncthreads();
    if (w < 3) {
        const float4* cb = (const float4*)&comb[w][lane][0];
        #pragma unroll
        for (int j = 0; j < 9; ++j) {
            float4 v = cb[j];
            acc[4*j] += v.x; acc[4*j+1] += v.y; acc[4*j+2] += v.z; acc[4*j+3] += v.w;
        }
    }
    __syncthreads();
    if (w == 1 || w == 2) {
        float4* cb = (float4*)&comb[w - 1][lane][0];
        #pragma unroll
        for (int j = 0; j < 9; ++j)
            cb[j] = make_float4(acc[4*j], acc[4*j+1], acc[4*j+2], acc[4*j+3]);
    }
    __syncthreads();
    if (w == 0) {
        #pragma unroll
        for (int j = 0; j < 9; ++j) {
            float4 v0 = ((const float4*)&comb[0][lane][0])[j];
            float4 v1 = ((const float4*)&comb[1][lane][0])[j];
            acc[4*j]   += v0.x + v1.x; acc[4*j+1] += v0.y + v1.y;
            acc[4*j+2] += v0.z + v1.z; acc[4*j+3] += v0.w + v1.w;
        }
        int u_g = u0 + lane;
        if (u_g < UN) {
            #pragma unroll
            for (int fo = 0; fo < F; ++fo) {
                float sc = bnz[4 * F + fo], oc = bnz[5 * F + fo];
                A[((size_t)(b * F + fo)) * UN + u_g] = elu_f(acc[fo] * sc + oc);
            }
        }
    }
}

// ---- K3: window sums over finished A + fused FC -> atomicAdd out -----------
__global__ __launch_bounds__(256) void k_wins(
    const float* __restrict__ A, const float* __restrict__ w_fc,
    float* __restrict__ out)
{
    __shared__ float Es[UN];
    __shared__ float G[GN];
    __shared__ float Ws[WN];
    __shared__ float Sm[M43];
    const int tid = threadIdx.x;
    const int bf = blockIdx.x;
    const int b = bf / F, f = bf % F;
    for (int i = tid; i < UN; i += 256)
        Es[i] = A[(size_t)bf * UN + i];
    __syncthreads();
    for (int q = tid; q < GN; q += 256)
        G[q] = Es[3 * q] + Es[3 * q + 1] + Es[3 * q + 2];
    __syncthreads();
    if (tid < WN) {
        float a = 0.f;
        for (int q = tid; q < tid + 167; ++q) a += G[q];
        Ws[tid] = a;
    }
    __syncthreads();
    if (tid < M43)
        Sm[tid] = (Ws[3 * tid] + Ws[3 * tid + 1] + Ws[3 * tid + 2]) * (1.f / 3.f);
    __syncthreads();
    if (tid < 4) {
        const float* wr = w_fc + tid * FLAT + f * M43;
        float a = 0.f;
        #pragma unroll 43
        for (int m = 0; m < M43; ++m) a += Sm[m] * wr[m];
        atomicAdd(&out[b * 4 + tid], a * (1.f / 501.f));
    }
}

extern "C" void kernel_launch(void* const* d_in, const int* in_sizes, int n_in,
                              void* d_out, int out_size, void* d_ws, size_t ws_size,
                              hipStream_t stream) {
    const float* x    = (const float*)d_in[0];
    const float* w_t  = (const float*)d_in[1];
    const float* b_t  = (const float*)d_in[2];
    const float* g_t  = (const float*)d_in[3];
    const float* be_t = (const float*)d_in[4];
    const float* m_t  = (const float*)d_in[5];
    const float* v_t  = (const float*)d_in[6];
    const float* w_s  = (const float*)d_in[7];
    const float* b_s  = (const float*)d_in[8];
    const float* g_s  = (const float*)d_in[9];
    const float* be_s = (const float*)d_in[10];
    const float* m_s  = (const float*)d_in[11];
    const float* v_s  = (const float*)d_in[12];
    const float* w_c  = (const float*)d_in[13];
    const float* b_c  = (const float*)d_in[14];
    const float* g_c  = (const float*)d_in[15];
    const float* be_c = (const float*)d_in[16];
    const float* m_c  = (const float*)d_in[17];
    const float* v_c  = (const float*)d_in[18];
    const float* w_fc = (const float*)d_in[19];
    const float* b_fc = (const float*)d_in[20];

    float* ws  = (float*)d_ws;
    float* h2  = ws + H2_OFF;
    float* A   = ws + A_OFF;
    float* wtT = ws + WTT_OFF;
    float* wsT = ws + WST_OFF;
    float* wcT = ws + WCT_OFF;
    float* bnz = ws + BN_OFF;
    float* out = (float*)d_out;

    k_prep<<<dim3(112), 256, 0, stream>>>(
        w_t, w_s, w_c, b_t, g_t, be_t, m_t, v_t,
        b_s, g_s, be_s, m_s, v_s, b_c, g_c, be_c, m_c, v_c, b_fc,
        wtT, wsT, wcT, bnz, out);

    k_fused<<<dim3(15, B), 1024, 0, stream>>>(x, wtT, wsT, bnz, h2);
    k_qconv<<<dim3(14, B), 768, 0, stream>>>(h2, wcT, bnz, A);
    k_wins<<<dim3(BF), 256, 0, stream>>>(A, w_fc, out);
}

// Round 5
// 190.084 us; speedup vs baseline: 1.2747x; 1.2466x over previous
//
#include <hip/hip_runtime.h>

#define EPS 1e-5f
#define B 16
#define CH 22
#define CH2 24            // padded channel count (rows 22,23 zero)
#define T_IN 1001
#define F 36
#define RF 65
#define T1 937            // T_IN - RF + 1
#define FC 792            // F*CH
#define UN 885            // valid u range for Q/E
#define PS3 112           // qconv staged span per f row (need 106, pad to 112)
#define KS 15
#define GN 295
#define WN 129
#define M43 43
#define BF 576            // B*F
#define FLAT 1548         // F*43

// workspace float offsets
#define H2_OFF  0                 // 576*937       =   539,712
#define A_OFF   539712            // A[bf][u]: 576*885 = 509,760
#define WTT_OFF 4617792           // + 65*36       =     2,340  (wtT[k][fi])
#define WST_OFF 4620132           // + 36*24*36    =    31,104  (wsTp, ch-padded)
#define WCT_OFF 4651236           // + 36*15*36    =    19,440
#define BN_OFF  4670676           // + 6*36        =       216

__device__ __forceinline__ float elu_f(float v) {
    return v > 0.f ? v : (__expf(v) - 1.f);
}

// ---- prep: transpose weights + bn scale/offset + init out with bias --------
__global__ __launch_bounds__(256) void k_prep(
    const float* __restrict__ w_t, const float* __restrict__ w_s,
    const float* __restrict__ w_c,
    const float* __restrict__ b_t, const float* __restrict__ g_t,
    const float* __restrict__ be_t,const float* __restrict__ m_t,
    const float* __restrict__ v_t,
    const float* __restrict__ b_s, const float* __restrict__ g_s,
    const float* __restrict__ be_s,const float* __restrict__ m_s,
    const float* __restrict__ v_s,
    const float* __restrict__ b_c, const float* __restrict__ g_c,
    const float* __restrict__ be_c,const float* __restrict__ m_c,
    const float* __restrict__ v_c, const float* __restrict__ b_fc,
    float* __restrict__ wtT, float* __restrict__ wsTp,
    float* __restrict__ wcT, float* __restrict__ bnz,
    float* __restrict__ out)
{
    int i = blockIdx.x * 256 + threadIdx.x;
    if (i < F * RF)     { int k = i / F,  fi = i % F; wtT[i] = w_t[fi * RF + k]; }
    if (i < F * CH2 * F) {                         // wsTp[(fi*24+ch)*F+fo], pad 0
        int fi = i / (CH2 * F);
        int r  = i % (CH2 * F);
        int ch = r / F, fo = r % F;
        wsTp[i] = (ch < CH) ? w_s[(fo * F + fi) * CH + ch] : 0.f;
    }
    if (i < F * KS * F) { int fk = i / F, fo = i % F; int f = fk / KS, k = fk % KS;
                          wcT[i] = w_c[(fo * F + f) * KS + k]; }
    if (i < F) {
        float s1 = g_t[i] * rsqrtf(v_t[i] + EPS);
        bnz[i]          = s1;
        bnz[F + i]      = (b_t[i] - m_t[i]) * s1 + be_t[i];
        float s2 = g_s[i] * rsqrtf(v_s[i] + EPS);
        bnz[2 * F + i]  = s2;
        bnz[3 * F + i]  = (b_s[i] - m_s[i]) * s2 + be_s[i];
        float s3 = g_c[i] * rsqrtf(v_c[i] + EPS);
        bnz[4 * F + i]  = s3;
        bnz[5 * F + i]  = (b_c[i] - m_c[i]) * s3 + be_c[i];
    }
    if (i < B * 4) out[i] = b_fc[i & 3];
}

// ---- K1: FUSED tconv + bn_t + elu + sconv + bn_s + elu  --------------------
// grid (15, B) = 240 blocks x 1024 thr = 16 waves (4/SIMD, 1 block/CU).
// Round-5 restructure vs round-4 (which was VALU-inst-bound, 4.5x FMA floor):
//   * k OUTER, ch inner: 9 temporal weights amortized over 6 channels
//     (54 FMA per weight fetch group vs 9 before).
//   * wtT staged in LDS, read as broadcast ds_read w/ imm offsets (no addr VALU).
//   * ch padded to 24 (x rows zeroed, wsTp rows zeroed): branch-free waves.
// h1a[6][9] in regs during k-loop; acc[36] materializes after -> peak ~110 VGPR.
__global__ __launch_bounds__(1024, 4) void k_fused(
    const float* __restrict__ x, const float* __restrict__ wtT,
    const float* __restrict__ wsTp, const float* __restrict__ bnz,
    float* __restrict__ h2)
{
    __shared__ float xs[CH2 * 128];       // 12.3 KB
    __shared__ float wts[RF * F];         //  9.4 KB
    __shared__ float comb[8][64][F];      // 73.7 KB  -> total 95.4 KB
    const int tid  = threadIdx.x;
    const int lane = tid & 63;
    const int w = __builtin_amdgcn_readfirstlane(tid >> 6);  // 0..15
    const int q = w >> 2;       // ch sextet (of CH2=24)
    const int g = w & 3;        // fi group
    const int b  = blockIdx.y;
    const int t0 = blockIdx.x * 64;

    // stage x window [24 ch][128 t] (pad ch>=22 with 0; clamp t)
    for (int i = tid; i < CH2 * 128; i += 1024) {
        int ch = i >> 7, j = i & 127;
        int t = t0 + j; if (t > T_IN - 1) t = T_IN - 1;
        xs[i] = (ch < CH) ? x[(b * CH + ch) * T_IN + t] : 0.f;
    }
    // stage temporal weights
    for (int i = tid; i < RF * F; i += 1024) wts[i] = wtT[i];
    __syncthreads();

    const int ch0 = q * 6;
    const int fi0 = g * 9;

    float h1a[6][9];
    #pragma unroll
    for (int c = 0; c < 6; ++c)
        #pragma unroll
        for (int j = 0; j < 9; ++j) h1a[c][j] = 0.f;

    const float* xb = xs + ch0 * 128 + lane;
    const float* wb = wts + fi0;

    #pragma unroll 4
    for (int k = 0; k < RF; ++k) {
        float wv[9];
        #pragma unroll
        for (int j = 0; j < 9; ++j)
            wv[j] = wb[k * F + j];                 // broadcast ds_read, imm off
        #pragma unroll
        for (int c = 0; c < 6; ++c) {
            float xv = xb[c * 128 + k];            // stride-1/lane, imm off
            #pragma unroll
            for (int j = 0; j < 9; ++j)
                h1a[c][j] += xv * wv[j];
        }
    }

    // bn_t + elu in-register
    #pragma unroll
    for (int j = 0; j < 9; ++j) {
        float s1 = bnz[fi0 + j], o1 = bnz[F + fi0 + j];
        #pragma unroll
        for (int c = 0; c < 6; ++c)
            h1a[c][j] = elu_f(h1a[c][j] * s1 + o1);
    }

    // sconv partial: acc[fo] += h1a[c][j] * wsTp[(fi0+j)*24 + ch0+c][fo]
    float acc[F];
    #pragma unroll
    for (int fo = 0; fo < F; ++fo) acc[fo] = 0.f;

    #pragma unroll
    for (int c = 0; c < 6; ++c) {
        #pragma unroll
        for (int j = 0; j < 9; ++j) {
            const float* wr = wsTp + ((fi0 + j) * CH2 + ch0 + c) * F;
            float e = h1a[c][j];
            #pragma unroll
            for (int fo = 0; fo < F; ++fo)
                acc[fo] += e * wr[fo];
        }
    }

    // combine 16 K-partials -> wave 0 (4 rounds, float4 LDS)
    for (int half = 8; half >= 1; half >>= 1) {
        if (w >= half && w < 2 * half) {
            float4* cb = (float4*)&comb[w - half][lane][0];
            #pragma unroll
            for (int j = 0; j < 9; ++j)
                cb[j] = make_float4(acc[4*j], acc[4*j+1], acc[4*j+2], acc[4*j+3]);
        }
        __syncthreads();
        if (w < half) {
            const float4* cb = (const float4*)&comb[w][lane][0];
            #pragma unroll
            for (int j = 0; j < 9; ++j) {
                float4 v = cb[j];
                acc[4*j]   += v.x; acc[4*j+1] += v.y;
                acc[4*j+2] += v.z; acc[4*j+3] += v.w;
            }
        }
        __syncthreads();
    }

    if (w == 0) {
        int t = t0 + lane;
        if (t < T1) {
            #pragma unroll
            for (int fo = 0; fo < F; ++fo) {
                float s2 = bnz[2 * F + fo], o2 = bnz[3 * F + fo];
                h2[(b * F + fo) * T1 + t] = elu_f(acc[fo] * s2 + o2);
            }
        }
    }
}

// ---- K2: fused pool3 + dilated conv + bn_c + elu -> A[bf][u] ---------------
// 12 waves, wave = 3-f K-slice with PRIVATE Ps staging (no barriers in main
// loop), acc[36] in registers, combine tree. (768, 3): 3 waves/SIMD cap.
__global__ __launch_bounds__(768, 3) void k_qconv(
    const float* __restrict__ h2, const float* __restrict__ wcT,
    const float* __restrict__ bnz, float* __restrict__ A)
{
    __shared__ float Ps[12][3][PS3];      // 16.1 KB
    __shared__ float comb[6][64][F];      // 55.3 KB
    const int tid  = threadIdx.x;
    const int lane = tid & 63;
    const int w = __builtin_amdgcn_readfirstlane(tid >> 6);  // 0..11
    const int b  = blockIdx.y;
    const int u0 = blockIdx.x * 64;
    const int f0 = w * 3;

    // per-wave private pooled staging (same-wave dep -> compiler lgkmcnt)
    for (int i = lane; i < 3 * PS3; i += 64) {
        int fl = i / PS3, j = i % PS3;
        const float* hr = h2 + (size_t)(b * F + f0 + fl) * T1;
        int s = u0 + j;
        int s0 = s     < T1 - 1 ? s     : T1 - 1;
        int s1 = s + 1 < T1 - 1 ? s + 1 : T1 - 1;
        int s2 = s + 2 < T1 - 1 ? s + 2 : T1 - 1;
        Ps[w][fl][j] = (hr[s0] + hr[s1] + hr[s2]) * (1.f / 3.f);
    }

    float acc[F];
    #pragma unroll
    for (int j = 0; j < F; ++j) acc[j] = 0.f;

    #pragma unroll
    for (int fl = 0; fl < 3; ++fl) {
        #pragma unroll
        for (int k = 0; k < KS; ++k) {
            float pv = Ps[w][fl][lane + 3 * k];
            const float* wr = wcT + ((f0 + fl) * KS + k) * F;  // 36 consec
            #pragma unroll
            for (int fo = 0; fo < F; ++fo) acc[fo] += pv * wr[fo];
        }
    }

    // combine 12 -> 1: rounds 6, 3, then 2-buffer finish
    if (w >= 6) {
        float4* cb = (float4*)&comb[w - 6][lane][0];
        #pragma unroll
        for (int j = 0; j < 9; ++j)
            cb[j] = make_float4(acc[4*j], acc[4*j+1], acc[4*j+2], acc[4*j+3]);
    }
    __syncthreads();
    if (w < 6) {
        const float4* cb = (const float4*)&comb[w][lane][0];
        #pragma unroll
        for (int j = 0; j < 9; ++j) {
            float4 v = cb[j];
            acc[4*j] += v.x; acc[4*j+1] += v.y; acc[4*j+2] += v.z; acc[4*j+3] += v.w;
        }
    }
    __syncthreads();
    if (w >= 3 && w < 6) {
        float4* cb = (float4*)&comb[w - 3][lane][0];
        #pragma unroll
        for (int j = 0; j < 9; ++j)
            cb[j] = make_float4(acc[4*j], acc[4*j+1], acc[4*j+2], acc[4*j+3]);
    }
    __syncthreads();
    if (w < 3) {
        const float4* cb = (const float4*)&comb[w][lane][0];
        #pragma unroll
        for (int j = 0; j < 9; ++j) {
            float4 v = cb[j];
            acc[4*j] += v.x; acc[4*j+1] += v.y; acc[4*j+2] += v.z; acc[4*j+3] += v.w;
        }
    }
    __syncthreads();
    if (w == 1 || w == 2) {
        float4* cb = (float4*)&comb[w - 1][lane][0];
        #pragma unroll
        for (int j = 0; j < 9; ++j)
            cb[j] = make_float4(acc[4*j], acc[4*j+1], acc[4*j+2], acc[4*j+3]);
    }
    __syncthreads();
    if (w == 0) {
        #pragma unroll
        for (int j = 0; j < 9; ++j) {
            float4 v0 = ((const float4*)&comb[0][lane][0])[j];
            float4 v1 = ((const float4*)&comb[1][lane][0])[j];
            acc[4*j]   += v0.x + v1.x; acc[4*j+1] += v0.y + v1.y;
            acc[4*j+2] += v0.z + v1.z; acc[4*j+3] += v0.w + v1.w;
        }
        int u_g = u0 + lane;
        if (u_g < UN) {
            #pragma unroll
            for (int fo = 0; fo < F; ++fo) {
                float sc = bnz[4 * F + fo], oc = bnz[5 * F + fo];
                A[((size_t)(b * F + fo)) * UN + u_g] = elu_f(acc[fo] * sc + oc);
            }
        }
    }
}

// ---- K3: window sums over finished A + fused FC -> atomicAdd out -----------
__global__ __launch_bounds__(256) void k_wins(
    const float* __restrict__ A, const float* __restrict__ w_fc,
    float* __restrict__ out)
{
    __shared__ float Es[UN];
    __shared__ float G[GN];
    __shared__ float Ws[WN];
    __shared__ float Sm[M43];
    const int tid = threadIdx.x;
    const int bf = blockIdx.x;
    const int b = bf / F, f = bf % F;
    for (int i = tid; i < UN; i += 256)
        Es[i] = A[(size_t)bf * UN + i];
    __syncthreads();
    for (int q = tid; q < GN; q += 256)
        G[q] = Es[3 * q] + Es[3 * q + 1] + Es[3 * q + 2];
    __syncthreads();
    if (tid < WN) {
        float a = 0.f;
        for (int q = tid; q < tid + 167; ++q) a += G[q];
        Ws[tid] = a;
    }
    __syncthreads();
    if (tid < M43)
        Sm[tid] = (Ws[3 * tid] + Ws[3 * tid + 1] + Ws[3 * tid + 2]) * (1.f / 3.f);
    __syncthreads();
    if (tid < 4) {
        const float* wr = w_fc + tid * FLAT + f * M43;
        float a = 0.f;
        #pragma unroll 43
        for (int m = 0; m < M43; ++m) a += Sm[m] * wr[m];
        atomicAdd(&out[b * 4 + tid], a * (1.f / 501.f));
    }
}

extern "C" void kernel_launch(void* const* d_in, const int* in_sizes, int n_in,
                              void* d_out, int out_size, void* d_ws, size_t ws_size,
                              hipStream_t stream) {
    const float* x    = (const float*)d_in[0];
    const float* w_t  = (const float*)d_in[1];
    const float* b_t  = (const float*)d_in[2];
    const float* g_t  = (const float*)d_in[3];
    const float* be_t = (const float*)d_in[4];
    const float* m_t  = (const float*)d_in[5];
    const float* v_t  = (const float*)d_in[6];
    const float* w_s  = (const float*)d_in[7];
    const float* b_s  = (const float*)d_in[8];
    const float* g_s  = (const float*)d_in[9];
    const float* be_s = (const float*)d_in[10];
    const float* m_s  = (const float*)d_in[11];
    const float* v_s  = (const float*)d_in[12];
    const float* w_c  = (const float*)d_in[13];
    const float* b_c  = (const float*)d_in[14];
    const float* g_c  = (const float*)d_in[15];
    const float* be_c = (const float*)d_in[16];
    const float* m_c  = (const float*)d_in[17];
    const float* v_c  = (const float*)d_in[18];
    const float* w_fc = (const float*)d_in[19];
    const float* b_fc = (const float*)d_in[20];

    float* ws   = (float*)d_ws;
    float* h2   = ws + H2_OFF;
    float* A    = ws + A_OFF;
    float* wtT  = ws + WTT_OFF;
    float* wsTp = ws + WST_OFF;
    float* wcT  = ws + WCT_OFF;
    float* bnz  = ws + BN_OFF;
    float* out  = (float*)d_out;

    k_prep<<<dim3(128), 256, 0, stream>>>(
        w_t, w_s, w_c, b_t, g_t, be_t, m_t, v_t,
        b_s, g_s, be_s, m_s, v_s, b_c, g_c, be_c, m_c, v_c, b_fc,
        wtT, wsTp, wcT, bnz, out);

    k_fused<<<dim3(15, B), 1024, 0, stream>>>(x, wtT, wsTp, bnz, h2);
    k_qconv<<<dim3(14, B), 768, 0, stream>>>(h2, wcT, bnz, A);
    k_wins<<<dim3(BF), 256, 0, stream>>>(A, w_fc, out);
}